// Round 7
// baseline (222.903 us; speedup 1.0000x reference)
//
#include <hip/hip_runtime.h>
#include <hip/hip_bf16.h>

#define CIN   256
#define COUT  32
#define IMG_H 96
#define IMG_W 96
#define HW    (IMG_H*IMG_W)
#define NB    2
#define NV    4
#define VSZ   64
#define NVOX  (VSZ*VSZ*VSZ)

typedef __attribute__((ext_vector_type(2))) float f32x2;

__device__ __forceinline__ float fast_exp2(float x) {
    float r;
    asm("v_exp_f32 %0, %1" : "=v"(r) : "v"(x));
    return r;
}

// Kernel 1 (R11): 1x1 conv, CIN-SPLIT. History: og-split baseline 44.7us
// (VALUBusy 22%: 256 loads per wave feeding only 2048 FMA = 8cyc compute
// per load -> latency never hides). R7/R8 VGPR-dbuf: 100/109us. R9 LDS
// staging: 122us. Fix the RATIO instead: wave og owns channels
// [og*64,og*64+64) and computes ALL 32 couts -> 64 loads per lane feed
// 2048 FMA = 32cyc/load; 32-load batches issue back-to-back and drain
// once per half-slab against ~2000cyc of compute. 4x read redundancy
// gone (distinct slabs per wave). Partials combined via 32KB LDS reduce.
__global__ __launch_bounds__(256) void conv1x1_kernel(
    const float* __restrict__ features,   // [B,V,CIN,H,W] fp32
    const float* __restrict__ Wp,         // [COUT,CIN]
    const float* __restrict__ bp,         // [COUT]
    __hip_bfloat16* __restrict__ out)     // [B,V,H,W,COUT] bf16
{
    __shared__ float red[4][COUT][64];             // 32 KB
    const int og   = __builtin_amdgcn_readfirstlane((threadIdx.x >> 6) & 3);
    const int lane = threadIdx.x & 63;
    const int bv   = blockIdx.y;
    const int px0  = blockIdx.x*64;
    const float* f = features + (size_t)bv*CIN*HW + (size_t)og*64*HW + px0 + lane;

    float acc[COUT];
    #pragma unroll
    for (int j = 0; j < COUT; ++j) acc[j] = 0.f;

    #pragma unroll
    for (int h = 0; h < 2; ++h) {                  // two 32-ch half-slabs
        float x[32];
        #pragma unroll
        for (int i = 0; i < 32; ++i)               // 32 coalesced loads in flight
            x[i] = f[(size_t)(h*32 + i)*HW];
        #pragma unroll
        for (int j = 0; j < COUT; ++j) {
            const float* wrow = Wp + (size_t)j*CIN + og*64 + h*32;  // uniform -> s_load
            float a0 = 0.f, a1 = 0.f, a2 = 0.f, a3 = 0.f;          // 4-way ILP chains
            #pragma unroll
            for (int i = 0; i < 32; i += 4) {
                a0 += x[i  ]*wrow[i  ];
                a1 += x[i+1]*wrow[i+1];
                a2 += x[i+2]*wrow[i+2];
                a3 += x[i+3]*wrow[i+3];
            }
            acc[j] += (a0 + a1) + (a2 + a3);
        }
    }

    #pragma unroll
    for (int j = 0; j < COUT; ++j)
        red[og][j][lane] = acc[j];                 // bank = lane%32: free
    __syncthreads();

    union { uint4 u4; __hip_bfloat16 hh[8]; } pk;  // wave og stores couts og*8..+8
    #pragma unroll
    for (int j = 0; j < 8; ++j) {
        const int ch = og*8 + j;                   // uniform -> bp via s_load
        pk.hh[j] = __float2bfloat16(red[0][ch][lane] + red[1][ch][lane]
                                  + red[2][ch][lane] + red[3][ch][lane] + bp[ch]);
    }
    *(uint4*)(out + ((size_t)(bv*HW + px0 + lane))*COUT + og*8) = pk.u4;
}

// Kernel 2 (R11): voxel-per-lane, R6 prefetch structure restored (skip
// REMOVED: refuted in R10 -- wave spans 64 z-voxels whose projections
// sweep an image line, predicate almost never fires, and the conditional
// cost the prefetch: 43 -> 47us). New: CROSS-CHUNK prefetch -- at the
// last view of a chunk, prefetch the next chunk's view-0 corners, so 8
// loads stay in flight continuously with no per-chunk cold start.
__global__ __launch_bounds__(256, 4) void volgen_kernel(
    const __hip_bfloat16* __restrict__ feats,  // [B,V,H,W,COUT] bf16
    const float* __restrict__ proj,            // [B,V,3,4]
    const float* __restrict__ coords,          // [B,NVOX,3]
    float* __restrict__ out)                   // [B,COUT,NVOX]
{
    const int tid = threadIdx.x;
    const int b   = blockIdx.y;
    const int n   = blockIdx.x*256 + tid;

    const float* cp = coords + ((size_t)b*NVOX + n)*3;
    const float X = cp[0], Y = cp[1], Z = cp[2];

    const float LOG2E = 1.4426950408889634f;

    int   off[NV][4];                          // byte offsets into feats
    float wgt[NV][4];                          // bilinear weight * log2(e)
    #pragma unroll
    for (int v = 0; v < NV; ++v) {
        const float* P = proj + (size_t)(b*NV + v)*12;   // uniform -> scalar
        const float wz = P[8]*X + P[9]*Y + P[10]*Z + P[11];
        const bool  vz = wz > 0.f;
        const float rz = __builtin_amdgcn_rcpf(wz);
        float px = (P[0]*X + P[1]*Y + P[2]*Z + P[3]) * rz * (95.f/96.f);
        float py = (P[4]*X + P[5]*Y + P[6]*Z + P[7]) * rz * (95.f/96.f);
        px = vz ? px : 0.f;  py = vz ? py : 0.f;
        px = fminf(fmaxf(px, -1.0e6f), 1.0e6f);
        py = fminf(fmaxf(py, -1.0e6f), 1.0e6f);
        const float fx0 = floorf(px), fy0 = floorf(py);
        const int x0 = (int)fx0, y0 = (int)fy0, x1 = x0+1, y1 = y0+1;
        const float wx1 = px - fx0, wx0 = 1.f - wx1;
        const float wy1 = py - fy0, wy0 = 1.f - wy1;
        const bool vx0 = (unsigned)x0 < (unsigned)IMG_W;
        const bool vx1 = (unsigned)x1 < (unsigned)IMG_W;
        const bool vy0 = (unsigned)y0 < (unsigned)IMG_H;
        const bool vy1 = (unsigned)y1 < (unsigned)IMG_H;
        const int cx0 = min(max(x0, 0), IMG_W-1), cx1 = min(max(x1, 0), IMG_W-1);
        const int cy0 = min(max(y0, 0), IMG_H-1), cy1 = min(max(y1, 0), IMG_H-1);
        const int base = ((b*NV + v)*HW)*COUT*2;         // bytes, uniform
        off[v][0] = base + (cy0*IMG_W + cx0)*(COUT*2);  wgt[v][0] = (vz & vx0 & vy0) ? wx0*wy0*LOG2E : 0.f;
        off[v][1] = base + (cy0*IMG_W + cx1)*(COUT*2);  wgt[v][1] = (vz & vx1 & vy0) ? wx1*wy0*LOG2E : 0.f;
        off[v][2] = base + (cy1*IMG_W + cx0)*(COUT*2);  wgt[v][2] = (vz & vx0 & vy1) ? wx0*wy1*LOG2E : 0.f;
        off[v][3] = base + (cy1*IMG_W + cx1)*(COUT*2);  wgt[v][3] = (vz & vx1 & vy1) ? wx1*wy1*LOG2E : 0.f;
    }

    const char* fb = (const char*)feats;
    const size_t ob = (size_t)b*COUT*NVOX + n;
    const float LN2 = 0.6931471805599453f;

    uint4 t[4], tn[4];
    #pragma unroll
    for (int c = 0; c < 4; ++c)                     // prime: chunk0 view0
        t[c] = *(const uint4*)(fb + off[0][c]);

    #pragma unroll
    for (int ch0 = 0; ch0 < COUT; ch0 += 8) {
        f32x2 A2[4], B2[4];

        #pragma unroll
        for (int v = 0; v < NV; ++v) {
            const bool last = (v == NV-1) && (ch0 + 8 >= COUT);
            if (!last) {                            // next view, or next chunk's view0
                const int nv  = (v < NV-1) ? v+1 : 0;
                const int nc0 = (v < NV-1) ? ch0 : ch0+8;
                #pragma unroll
                for (int c = 0; c < 4; ++c)
                    tn[c] = *(const uint4*)(fb + off[nv][c] + nc0*2);
            }

            f32x2 s2[4];
            #pragma unroll
            for (int c = 0; c < 4; ++c) {
                const float w = wgt[v][c];
                const f32x2 w2 = { w, w };
                const unsigned tu[4] = { t[c].x, t[c].y, t[c].z, t[c].w };
                #pragma unroll
                for (int k = 0; k < 4; ++k) {       // packed fma: 2 ch/instr
                    f32x2 f2;
                    f2.x = __uint_as_float(tu[k] << 16);
                    f2.y = __uint_as_float(tu[k] & 0xffff0000u);
                    if (c == 0) s2[k] = w2 * f2;    // no zero-init
                    else        s2[k] += w2 * f2;
                }
            }

            #pragma unroll
            for (int k = 0; k < 4; ++k) {
                f32x2 e2;
                e2.x = fast_exp2(s2[k].x);          // wgt pre-scaled: 2^s' = e^s
                e2.y = fast_exp2(s2[k].y);
                if (v == 0) { A2[k] = e2;  B2[k] = s2[k]*e2; }
                else        { A2[k] += e2; B2[k] += s2[k]*e2; }
            }

            if (!last) {
                #pragma unroll
                for (int c = 0; c < 4; ++c) t[c] = tn[c];   // rotate
            }
        }

        #pragma unroll
        for (int k = 0; k < 4; ++k) {               // coalesced stores
            out[ob + (size_t)(ch0 + 2*k    )*NVOX] = B2[k].x * __builtin_amdgcn_rcpf(A2[k].x) * LN2;
            out[ob + (size_t)(ch0 + 2*k + 1)*NVOX] = B2[k].y * __builtin_amdgcn_rcpf(A2[k].y) * LN2;
        }
    }
}

extern "C" void kernel_launch(void* const* d_in, const int* in_sizes, int n_in,
                              void* d_out, int out_size, void* d_ws, size_t ws_size,
                              hipStream_t stream)
{
    const float* features = (const float*)d_in[0];   // [2,4,256,96,96]
    const float* proj     = (const float*)d_in[1];   // [2,4,3,4]
    const float* coords   = (const float*)d_in[2];   // [2,64,64,64,3]
    const float* Wp       = (const float*)d_in[3];   // [32,256]
    const float* bp       = (const float*)d_in[4];   // [32]
    float* out = (float*)d_out;                      // [2,32,64,64,64]
    __hip_bfloat16* featsT = (__hip_bfloat16*)d_ws;  // [2,4,96,96,32] bf16 = 4.72 MB

    hipLaunchKernelGGL(conv1x1_kernel, dim3(HW/64, NB*NV), dim3(256), 0, stream,
                       features, Wp, bp, featsT);
    hipLaunchKernelGGL(volgen_kernel, dim3(NVOX/256, NB), dim3(256), 0, stream,
                       featsT, proj, coords, out);
}

// Round 8
// 208.450 us; speedup vs baseline: 1.0693x; 1.0693x over previous
//
#include <hip/hip_runtime.h>
#include <hip/hip_bf16.h>

#define CIN   256
#define COUT  32
#define IMG_H 96
#define IMG_W 96
#define HW    (IMG_H*IMG_W)
#define NB    2
#define NV    4
#define VSZ   64
#define NVOX  (VSZ*VSZ*VSZ)

typedef __attribute__((ext_vector_type(2))) float f32x2;

__device__ __forceinline__ float fast_exp2(float x) {
    float r;
    asm("v_exp_f32 %0, %1" : "=v"(r) : "v"(x));
    return r;
}

// Kernel 1 (R12): 1x1 conv, K-SPLIT x2 via 512-thr blocks.
// History: R6 og-split 44.7us (VGPR 16, occ 37%, grid caps at 4608 waves
// = 56% of 8192 slots). R7/R8 VGPR-dbuf: 100/109us (occupancy paid).
// R9 LDS-stage: 122us. R11 CIN-split: 89us (compiler loop-interchange
// sank loads, VGPR 44). Law: hipcc sinks load batches unless structurally
// forced; forcing costs occupancy. So raise WAVE COUNT instead: 8 waves =
// 4 og x 2 K-halves, each wave = R6 inner structure verbatim on 128
// channels -> 2x waves (9216, 112% cap) -> 2x outstanding loads/CU.
// Partials combined via 16KB LDS reduce (2-way bank access, free).
__global__ __launch_bounds__(512) void conv1x1_kernel(
    const float* __restrict__ features,   // [B,V,CIN,H,W] fp32
    const float* __restrict__ Wp,         // [COUT,CIN]
    const float* __restrict__ bp,         // [COUT]
    __hip_bfloat16* __restrict__ out)     // [B,V,H,W,COUT] bf16
{
    __shared__ float red[COUT][2][64];             // 16 KB
    const int wid  = threadIdx.x >> 6;             // 0..7
    const int og   = __builtin_amdgcn_readfirstlane(wid & 3);
    const int kh   = __builtin_amdgcn_readfirstlane(wid >> 2);  // K-half
    const int lane = threadIdx.x & 63;
    const int bv   = blockIdx.y;
    const int px   = blockIdx.x*64 + lane;
    const float* f     = features + (size_t)bv*CIN*HW + (size_t)kh*128*HW + px;
    const float* wbase = Wp + (size_t)og*8*CIN + kh*128;   // uniform -> scalar

    float acc[8];
    #pragma unroll
    for (int j = 0; j < 8; ++j) acc[j] = 0.f;      // bias added at reduce

    for (int cc = 0; cc < 128; cc += 8) {          // R6 inner, half the K
        float x[8];
        #pragma unroll
        for (int i = 0; i < 8; ++i)                // 8 indep coalesced loads
            x[i] = f[(size_t)(cc + i)*HW];
        #pragma unroll
        for (int i = 0; i < 8; ++i) {
            #pragma unroll
            for (int j = 0; j < 8; ++j)            // v_fmac v, s, v
                acc[j] += x[i] * wbase[(size_t)j*CIN + cc + i];
        }
    }

    #pragma unroll
    for (int j = 0; j < 8; ++j)
        red[og*8 + j][kh][lane] = acc[j];          // bank = lane%32: free
    __syncthreads();

    if (kh == 0) {                                 // waves 0-3 finalize+store
        union { uint4 u4; __hip_bfloat16 hh[8]; } pk;
        #pragma unroll
        for (int j = 0; j < 8; ++j) {
            const int ch = og*8 + j;               // uniform -> bp via s_load
            pk.hh[j] = __float2bfloat16(red[ch][0][lane] + red[ch][1][lane] + bp[ch]);
        }
        *(uint4*)(out + ((size_t)(bv*HW + px))*COUT + og*8) = pk.u4;
    }
}

// Kernel 2 (R12): voxel-per-lane, DEPTH-2 software pipeline.
// R11 post-mortem: volgen ~46us, VALUBusy ~45% -> ~55% latency-stalled
// with only 4 gathers in flight. Flat 16-stage loop (chunk x view), fully
// unrolled so t/tn/tnn rotation is pure register renaming; loads for
// stage s+2 issue while computing stage s -> 8 gathers in flight.
__global__ __launch_bounds__(256, 4) void volgen_kernel(
    const __hip_bfloat16* __restrict__ feats,  // [B,V,H,W,COUT] bf16
    const float* __restrict__ proj,            // [B,V,3,4]
    const float* __restrict__ coords,          // [B,NVOX,3]
    float* __restrict__ out)                   // [B,COUT,NVOX]
{
    const int tid = threadIdx.x;
    const int b   = blockIdx.y;
    const int n   = blockIdx.x*256 + tid;

    const float* cp = coords + ((size_t)b*NVOX + n)*3;
    const float X = cp[0], Y = cp[1], Z = cp[2];

    const float LOG2E = 1.4426950408889634f;

    int   off[NV][4];                          // byte offsets into feats
    float wgt[NV][4];                          // bilinear weight * log2(e)
    #pragma unroll
    for (int v = 0; v < NV; ++v) {
        const float* P = proj + (size_t)(b*NV + v)*12;   // uniform -> scalar
        const float wz = P[8]*X + P[9]*Y + P[10]*Z + P[11];
        const bool  vz = wz > 0.f;
        const float rz = __builtin_amdgcn_rcpf(wz);
        float px = (P[0]*X + P[1]*Y + P[2]*Z + P[3]) * rz * (95.f/96.f);
        float py = (P[4]*X + P[5]*Y + P[6]*Z + P[7]) * rz * (95.f/96.f);
        px = vz ? px : 0.f;  py = vz ? py : 0.f;
        px = fminf(fmaxf(px, -1.0e6f), 1.0e6f);
        py = fminf(fmaxf(py, -1.0e6f), 1.0e6f);
        const float fx0 = floorf(px), fy0 = floorf(py);
        const int x0 = (int)fx0, y0 = (int)fy0, x1 = x0+1, y1 = y0+1;
        const float wx1 = px - fx0, wx0 = 1.f - wx1;
        const float wy1 = py - fy0, wy0 = 1.f - wy1;
        const bool vx0 = (unsigned)x0 < (unsigned)IMG_W;
        const bool vx1 = (unsigned)x1 < (unsigned)IMG_W;
        const bool vy0 = (unsigned)y0 < (unsigned)IMG_H;
        const bool vy1 = (unsigned)y1 < (unsigned)IMG_H;
        const int cx0 = min(max(x0, 0), IMG_W-1), cx1 = min(max(x1, 0), IMG_W-1);
        const int cy0 = min(max(y0, 0), IMG_H-1), cy1 = min(max(y1, 0), IMG_H-1);
        const int base = ((b*NV + v)*HW)*COUT*2;         // bytes, uniform
        off[v][0] = base + (cy0*IMG_W + cx0)*(COUT*2);  wgt[v][0] = (vz & vx0 & vy0) ? wx0*wy0*LOG2E : 0.f;
        off[v][1] = base + (cy0*IMG_W + cx1)*(COUT*2);  wgt[v][1] = (vz & vx1 & vy0) ? wx1*wy0*LOG2E : 0.f;
        off[v][2] = base + (cy1*IMG_W + cx0)*(COUT*2);  wgt[v][2] = (vz & vx0 & vy1) ? wx0*wy1*LOG2E : 0.f;
        off[v][3] = base + (cy1*IMG_W + cx1)*(COUT*2);  wgt[v][3] = (vz & vx1 & vy1) ? wx1*wy1*LOG2E : 0.f;
    }

    const char* fb = (const char*)feats;
    const size_t ob = (size_t)b*COUT*NVOX + n;
    const float LN2 = 0.6931471805599453f;

    uint4 t[4], tn[4], tnn[4];
    #pragma unroll
    for (int c = 0; c < 4; ++c)                     // prime stage 0 (v0,ch0)
        t[c] = *(const uint4*)(fb + off[0][c]);
    #pragma unroll
    for (int c = 0; c < 4; ++c)                     // prime stage 1 (v1,ch0)
        tn[c] = *(const uint4*)(fb + off[1][c]);

    f32x2 A2[4], B2[4];

    #pragma unroll
    for (int s = 0; s < 16; ++s) {                  // stage = chunk*4 + view
        const int v   = s & 3;
        const int ch0 = (s >> 2) * 8;

        if (s + 2 < 16) {                           // issue stage s+2: 8 in flight
            const int v2  = (s+2) & 3;
            const int c20 = ((s+2) >> 2) * 8;
            #pragma unroll
            for (int c = 0; c < 4; ++c)
                tnn[c] = *(const uint4*)(fb + off[v2][c] + c20*2);
        }

        f32x2 s2[4];
        #pragma unroll
        for (int c = 0; c < 4; ++c) {
            const float w = wgt[v][c];
            const f32x2 w2 = { w, w };
            const unsigned tu[4] = { t[c].x, t[c].y, t[c].z, t[c].w };
            #pragma unroll
            for (int k = 0; k < 4; ++k) {           // packed fma: 2 ch/instr
                f32x2 f2;
                f2.x = __uint_as_float(tu[k] << 16);
                f2.y = __uint_as_float(tu[k] & 0xffff0000u);
                if (c == 0) s2[k] = w2 * f2;        // no zero-init
                else        s2[k] += w2 * f2;
            }
        }

        #pragma unroll
        for (int k = 0; k < 4; ++k) {
            f32x2 e2;
            e2.x = fast_exp2(s2[k].x);              // wgt pre-scaled: 2^s' = e^s
            e2.y = fast_exp2(s2[k].y);
            if (v == 0) { A2[k] = e2;  B2[k] = s2[k]*e2; }
            else        { A2[k] += e2; B2[k] += s2[k]*e2; }
        }

        if (v == 3) {                               // chunk done -> store
            #pragma unroll
            for (int k = 0; k < 4; ++k) {           // coalesced stores
                out[ob + (size_t)(ch0 + 2*k    )*NVOX] = B2[k].x * __builtin_amdgcn_rcpf(A2[k].x) * LN2;
                out[ob + (size_t)(ch0 + 2*k + 1)*NVOX] = B2[k].y * __builtin_amdgcn_rcpf(A2[k].y) * LN2;
            }
        }

        #pragma unroll
        for (int c = 0; c < 4; ++c) { t[c] = tn[c]; tn[c] = tnn[c]; }  // rename
    }
}

extern "C" void kernel_launch(void* const* d_in, const int* in_sizes, int n_in,
                              void* d_out, int out_size, void* d_ws, size_t ws_size,
                              hipStream_t stream)
{
    const float* features = (const float*)d_in[0];   // [2,4,256,96,96]
    const float* proj     = (const float*)d_in[1];   // [2,4,3,4]
    const float* coords   = (const float*)d_in[2];   // [2,64,64,64,3]
    const float* Wp       = (const float*)d_in[3];   // [32,256]
    const float* bp       = (const float*)d_in[4];   // [32]
    float* out = (float*)d_out;                      // [2,32,64,64,64]
    __hip_bfloat16* featsT = (__hip_bfloat16*)d_ws;  // [2,4,96,96,32] bf16 = 4.72 MB

    hipLaunchKernelGGL(conv1x1_kernel, dim3(HW/64, NB*NV), dim3(512), 0, stream,
                       features, Wp, bp, featsT);
    hipLaunchKernelGGL(volgen_kernel, dim3(NVOX/256, NB), dim3(256), 0, stream,
                       featsT, proj, coords, out);
}

// Round 9
// 179.753 us; speedup vs baseline: 1.2401x; 1.1596x over previous
//
#include <hip/hip_runtime.h>
#include <hip/hip_bf16.h>

#define CIN   256
#define COUT  32
#define IMG_H 96
#define IMG_W 96
#define HW    (IMG_H*IMG_W)
#define NB    2
#define NV    4
#define VSZ   64
#define NVOX  (VSZ*VSZ*VSZ)

typedef __attribute__((ext_vector_type(2))) float f32x2;

__device__ __forceinline__ float fast_exp2(float x) {
    float r;
    asm("v_exp_f32 %0, %1" : "=v"(r) : "v"(x));
    return r;
}

// Kernel 1 (R13): 1x1 conv, og x2 / kh x2 / px x2 (512-thr blocks).
// R12 verdict: 2x waves at constant demand = NULL -> conv is BW-bound at
// ~6.8 TB/s on its DEMAND traffic (R6: 302 MB 4x-og-redundant = 44.7us).
// Only lever: cut traffic. Each wave now computes 16 couts over its own
// 128-channel half for its own 64 px -> duplication 4x -> 2x, demand
// 151 MB -> ~22-28us. Inner loop keeps R6's exact texture (8-load batch,
// i-outer j-inner fmac, scalar weights). kh-partials via 32KB LDS reduce.
__global__ __launch_bounds__(512) void conv1x1_kernel(
    const float* __restrict__ features,   // [B,V,CIN,H,W] fp32
    const float* __restrict__ Wp,         // [COUT,CIN]
    const float* __restrict__ bp,         // [COUT]
    __hip_bfloat16* __restrict__ out)     // [B,V,H,W,COUT] bf16
{
    __shared__ float red[2][COUT][128];            // [kh][cout][pxl] 32 KB
    const int wid  = threadIdx.x >> 6;             // 0..7
    const int pxs  = __builtin_amdgcn_readfirstlane(wid & 1);
    const int og   = __builtin_amdgcn_readfirstlane((wid >> 1) & 1);
    const int kh   = __builtin_amdgcn_readfirstlane(wid >> 2);
    const int lane = threadIdx.x & 63;
    const int pxl  = pxs*64 + lane;                // 0..127 within block
    const int bv   = blockIdx.y;
    const int px   = blockIdx.x*128 + pxl;
    const float* f     = features + (size_t)bv*CIN*HW + (size_t)kh*128*HW + px;
    const float* wbase = Wp + (size_t)og*16*CIN + kh*128;  // uniform -> scalar

    float acc[16];
    #pragma unroll
    for (int j = 0; j < 16; ++j) acc[j] = 0.f;     // bias added at reduce

    for (int cc = 0; cc < 128; cc += 8) {          // R6 inner texture
        float x[8];
        #pragma unroll
        for (int i = 0; i < 8; ++i)                // 8 indep coalesced loads
            x[i] = f[(size_t)(cc + i)*HW];
        #pragma unroll
        for (int i = 0; i < 8; ++i) {
            #pragma unroll
            for (int j = 0; j < 16; ++j)           // v_fmac v, s, v
                acc[j] += x[i] * wbase[(size_t)j*CIN + cc + i];
        }
    }

    #pragma unroll
    for (int j = 0; j < 16; ++j)
        red[kh][og*16 + j][pxl] = acc[j];          // banks 0..31 x2: free
    __syncthreads();

    if (kh == 0) {                                 // 4 waves finalize + store
        union { uint4 u4[2]; __hip_bfloat16 hh[16]; } pk;
        #pragma unroll
        for (int j = 0; j < 16; ++j) {
            const int ch = og*16 + j;              // uniform -> bp via s_load
            pk.hh[j] = __float2bfloat16(red[0][ch][pxl] + red[1][ch][pxl] + bp[ch]);
        }
        __hip_bfloat16* op = out + (size_t)(bv*HW + px)*COUT + og*16;
        *(uint4*)(op)     = pk.u4[0];
        *(uint4*)(op + 8) = pk.u4[1];
    }
}

// Kernel 2 (R13 = R6 verbatim, best measured ~43us): voxel-per-lane,
// chunk-major, depth-1 view prefetch. R10 skip refuted (predicate never
// fires). R12 depth-2 flat pipeline refuted HARD: longer reuse distance
// thrashed the 4-MiB XCD L2 (featsT=4.72MB sits at the capacity edge):
// FETCH 5.6->52MB, WRITE 65->147MB, 46->69us. Keep reuse distance SHORT.
__global__ __launch_bounds__(256, 4) void volgen_kernel(
    const __hip_bfloat16* __restrict__ feats,  // [B,V,H,W,COUT] bf16
    const float* __restrict__ proj,            // [B,V,3,4]
    const float* __restrict__ coords,          // [B,NVOX,3]
    float* __restrict__ out)                   // [B,COUT,NVOX]
{
    const int tid = threadIdx.x;
    const int b   = blockIdx.y;
    const int n   = blockIdx.x*256 + tid;

    const float* cp = coords + ((size_t)b*NVOX + n)*3;
    const float X = cp[0], Y = cp[1], Z = cp[2];

    const float LOG2E = 1.4426950408889634f;

    int   off[NV][4];                          // byte offsets into feats
    float wgt[NV][4];                          // bilinear weight * log2(e)
    #pragma unroll
    for (int v = 0; v < NV; ++v) {
        const float* P = proj + (size_t)(b*NV + v)*12;   // uniform -> scalar
        const float wz = P[8]*X + P[9]*Y + P[10]*Z + P[11];
        const bool  vz = wz > 0.f;
        const float rz = __builtin_amdgcn_rcpf(wz);
        float px = (P[0]*X + P[1]*Y + P[2]*Z + P[3]) * rz * (95.f/96.f);
        float py = (P[4]*X + P[5]*Y + P[6]*Z + P[7]) * rz * (95.f/96.f);
        px = vz ? px : 0.f;  py = vz ? py : 0.f;
        px = fminf(fmaxf(px, -1.0e6f), 1.0e6f);
        py = fminf(fmaxf(py, -1.0e6f), 1.0e6f);
        const float fx0 = floorf(px), fy0 = floorf(py);
        const int x0 = (int)fx0, y0 = (int)fy0, x1 = x0+1, y1 = y0+1;
        const float wx1 = px - fx0, wx0 = 1.f - wx1;
        const float wy1 = py - fy0, wy0 = 1.f - wy1;
        const bool vx0 = (unsigned)x0 < (unsigned)IMG_W;
        const bool vx1 = (unsigned)x1 < (unsigned)IMG_W;
        const bool vy0 = (unsigned)y0 < (unsigned)IMG_H;
        const bool vy1 = (unsigned)y1 < (unsigned)IMG_H;
        const int cx0 = min(max(x0, 0), IMG_W-1), cx1 = min(max(x1, 0), IMG_W-1);
        const int cy0 = min(max(y0, 0), IMG_H-1), cy1 = min(max(y1, 0), IMG_H-1);
        const int base = ((b*NV + v)*HW)*COUT*2;         // bytes, uniform
        off[v][0] = base + (cy0*IMG_W + cx0)*(COUT*2);  wgt[v][0] = (vz & vx0 & vy0) ? wx0*wy0*LOG2E : 0.f;
        off[v][1] = base + (cy0*IMG_W + cx1)*(COUT*2);  wgt[v][1] = (vz & vx1 & vy0) ? wx1*wy0*LOG2E : 0.f;
        off[v][2] = base + (cy1*IMG_W + cx0)*(COUT*2);  wgt[v][2] = (vz & vx0 & vy1) ? wx0*wy1*LOG2E : 0.f;
        off[v][3] = base + (cy1*IMG_W + cx1)*(COUT*2);  wgt[v][3] = (vz & vx1 & vy1) ? wx1*wy1*LOG2E : 0.f;
    }

    const char* fb = (const char*)feats;
    const size_t ob = (size_t)b*COUT*NVOX + n;
    const float LN2 = 0.6931471805599453f;

    for (int ch0 = 0; ch0 < COUT; ch0 += 8) {
        f32x2 A2[4], B2[4];
        uint4 t[4], tn[4];

        #pragma unroll
        for (int c = 0; c < 4; ++c)                     // prime the pipeline
            t[c] = *(const uint4*)(fb + off[0][c] + ch0*2);

        #pragma unroll
        for (int v = 0; v < NV; ++v) {
            if (v < NV-1) {
                #pragma unroll
                for (int c = 0; c < 4; ++c)             // prefetch next view
                    tn[c] = *(const uint4*)(fb + off[v+1][c] + ch0*2);
            }

            f32x2 s2[4];
            #pragma unroll
            for (int c = 0; c < 4; ++c) {
                const float w = wgt[v][c];
                const f32x2 w2 = { w, w };
                const unsigned tu[4] = { t[c].x, t[c].y, t[c].z, t[c].w };
                #pragma unroll
                for (int k = 0; k < 4; ++k) {           // packed fma: 2 ch/instr
                    f32x2 f2;
                    f2.x = __uint_as_float(tu[k] << 16);
                    f2.y = __uint_as_float(tu[k] & 0xffff0000u);
                    if (c == 0) s2[k] = w2 * f2;        // no zero-init
                    else        s2[k] += w2 * f2;
                }
            }

            #pragma unroll
            for (int k = 0; k < 4; ++k) {
                f32x2 e2;
                e2.x = fast_exp2(s2[k].x);              // wgt pre-scaled: 2^s' = e^s
                e2.y = fast_exp2(s2[k].y);
                if (v == 0) { A2[k] = e2;  B2[k] = s2[k]*e2; }
                else        { A2[k] += e2; B2[k] += s2[k]*e2; }
            }

            if (v < NV-1) {
                #pragma unroll
                for (int c = 0; c < 4; ++c) t[c] = tn[c];   // rotate
            }
        }

        #pragma unroll
        for (int k = 0; k < 4; ++k) {                   // coalesced stores
            out[ob + (size_t)(ch0 + 2*k    )*NVOX] = B2[k].x * __builtin_amdgcn_rcpf(A2[k].x) * LN2;
            out[ob + (size_t)(ch0 + 2*k + 1)*NVOX] = B2[k].y * __builtin_amdgcn_rcpf(A2[k].y) * LN2;
        }
    }
}

extern "C" void kernel_launch(void* const* d_in, const int* in_sizes, int n_in,
                              void* d_out, int out_size, void* d_ws, size_t ws_size,
                              hipStream_t stream)
{
    const float* features = (const float*)d_in[0];   // [2,4,256,96,96]
    const float* proj     = (const float*)d_in[1];   // [2,4,3,4]
    const float* coords   = (const float*)d_in[2];   // [2,64,64,64,3]
    const float* Wp       = (const float*)d_in[3];   // [32,256]
    const float* bp       = (const float*)d_in[4];   // [32]
    float* out = (float*)d_out;                      // [2,32,64,64,64]
    __hip_bfloat16* featsT = (__hip_bfloat16*)d_ws;  // [2,4,96,96,32] bf16 = 4.72 MB

    hipLaunchKernelGGL(conv1x1_kernel, dim3(HW/128, NB*NV), dim3(512), 0, stream,
                       features, Wp, bp, featsT);
    hipLaunchKernelGGL(volgen_kernel, dim3(NVOX/256, NB), dim3(256), 0, stream,
                       featsT, proj, coords, out);
}